// Round 2
// baseline (657.478 us; speedup 1.0000x reference)
//
#include <hip/hip_runtime.h>

// AdaptiveStdPooling2d: x [B=16, C=128, H=512, W=128] fp32  (NOTE: H=512, W=128)
// H_OUT=8, W_OUT=16  ->  kh = 64 (variance axis), kw = 8 (std-sum axis)
// out[b,c,ho,wo] = sum_{j<8} sqrt( var_{r<64}( x[b,c,ho*64+r, wo*8+j] ) + 1e-14 )
//
// Slab (b,c,ho) = 64 rows x 128 cols = contiguous 32 KiB of x.
// One wave per slab; 4 waves per 256-thread block -> 4096 blocks.
// Lane layout: cg = lane&31 owns columns 4cg..4cg+3 (float4),
//              rh = lane>>5 owns rows [32*rh, 32*rh+32).
// Row-half combine: __shfl_xor 32 (in-wave). kw=8 bin = 2 lanes: __shfl_xor 1.

#define KH 64
#define KW 8
#define WIDTH 128
#define W_OUT 16
#define SLABS 16384   // B*C*H_OUT = 16*128*8

__global__ __launch_bounds__(256) void adaptive_std_pool_kernel(
    const float* __restrict__ x, float* __restrict__ out) {
    const int wave = threadIdx.x >> 6;     // 0..3
    const int lane = threadIdx.x & 63;
    const int slab = blockIdx.x * 4 + wave;  // [0, 16384)

    const int cg = lane & 31;              // column group: cols 4cg..4cg+3
    const int rh = lane >> 5;              // row half: rows [32rh, 32rh+32)

    const float4* p = (const float4*)(x + (size_t)slab * KH * WIDTH)
                      + (size_t)rh * 32 * (WIDTH / 4) + cg;

    float4 s  = {0.f, 0.f, 0.f, 0.f};
    float4 ss = {0.f, 0.f, 0.f, 0.f};
#pragma unroll
    for (int r = 0; r < 32; ++r) {
        float4 v = p[(size_t)r * (WIDTH / 4)];
        s.x += v.x; s.y += v.y; s.z += v.z; s.w += v.w;
        ss.x = fmaf(v.x, v.x, ss.x);
        ss.y = fmaf(v.y, v.y, ss.y);
        ss.z = fmaf(v.z, v.z, ss.z);
        ss.w = fmaf(v.w, v.w, ss.w);
    }

    // Combine the two row-halves (lane ^ 32, stays in the 64-lane wave).
    s.x  += __shfl_xor(s.x, 32);  s.y  += __shfl_xor(s.y, 32);
    s.z  += __shfl_xor(s.z, 32);  s.w  += __shfl_xor(s.w, 32);
    ss.x += __shfl_xor(ss.x, 32); ss.y += __shfl_xor(ss.y, 32);
    ss.z += __shfl_xor(ss.z, 32); ss.w += __shfl_xor(ss.w, 32);

    const float inv = 1.0f / (float)KH;
    float partial = 0.f;
    {
        float m = s.x * inv;
        partial += sqrtf(fmaxf(ss.x * inv - m * m, 0.f) + 1e-14f);
    }
    {
        float m = s.y * inv;
        partial += sqrtf(fmaxf(ss.y * inv - m * m, 0.f) + 1e-14f);
    }
    {
        float m = s.z * inv;
        partial += sqrtf(fmaxf(ss.z * inv - m * m, 0.f) + 1e-14f);
    }
    {
        float m = s.w * inv;
        partial += sqrtf(fmaxf(ss.w * inv - m * m, 0.f) + 1e-14f);
    }

    // kw=8 bin = columns {4*(2m), .., 4*(2m)+7} = lanes 2m, 2m+1 (aligned pair).
    partial += __shfl_xor(partial, 1);

    if (rh == 0 && (lane & 1) == 0) {
        out[slab * W_OUT + (cg >> 1)] = partial;
    }
}

extern "C" void kernel_launch(void* const* d_in, const int* in_sizes, int n_in,
                              void* d_out, int out_size, void* d_ws, size_t ws_size,
                              hipStream_t stream) {
    const float* x = (const float*)d_in[0];
    float* out = (float*)d_out;
    adaptive_std_pool_kernel<<<SLABS / 4, 256, 0, stream>>>(x, out);
}

// Round 3
// 642.916 us; speedup vs baseline: 1.0227x; 1.0227x over previous
//
#include <hip/hip_runtime.h>

// AdaptiveStdPooling2d: x [B=16, C=128, H=512, W=128] fp32
// H_OUT=8, W_OUT=16  ->  kh = 64 (variance axis), kw = 8 (std-sum axis)
// out[b,c,ho,wo] = sum_{j<8} sqrt( var_{r<64}( x[b,c,ho*64+r, wo*8+j] ) + 1e-14 )
//
// Slab (b,c,ho) = 64 rows x 128 cols = contiguous 32 KiB of x.
// One wave per slab; 4 waves per 256-thread block -> 4096 blocks.
// Lane layout: cg = lane&31 owns columns 4cg..4cg+3 (float4),
//              rh = lane>>5 owns rows {2k + rh}, k=0..31  -> each wave load
//              instruction covers rows {2k,2k+1} = ONE contiguous 1-KiB segment
//              (ideal 16 B/lane x 64-lane coalescing unit).
// Input is read exactly once -> nontemporal loads (skip L2 fill).

#define KH 64
#define WIDTH 128
#define W_OUT 16
#define SLABS 16384   // B*C*H_OUT = 16*128*8

typedef float f32x4 __attribute__((ext_vector_type(4)));

__global__ __launch_bounds__(256) void adaptive_std_pool_kernel(
    const float* __restrict__ x, float* __restrict__ out) {
    const int wave = threadIdx.x >> 6;       // 0..3
    const int lane = threadIdx.x & 63;
    const int slab = blockIdx.x * 4 + wave;  // [0, 16384)

    const int cg = lane & 31;                // column group: cols 4cg..4cg+3
    const int rh = lane >> 5;                // row parity: rows 2k+rh

    const f32x4* p = (const f32x4*)(x + (size_t)slab * KH * WIDTH)
                     + (size_t)rh * (WIDTH / 4) + cg;

    f32x4 s  = {0.f, 0.f, 0.f, 0.f};
    f32x4 ss = {0.f, 0.f, 0.f, 0.f};
#pragma unroll
    for (int k = 0; k < 32; ++k) {
        // rows {2k, 2k+1}: stride 2 rows = 64 float4 = 1 KiB
        f32x4 v = __builtin_nontemporal_load(p + (size_t)k * (2 * WIDTH / 4));
        s += v;
        ss += v * v;   // -ffp-contract fuses into v_fmac
    }

    // Combine the two row-parity halves (lane ^ 32, stays in the 64-lane wave).
    s.x  += __shfl_xor(s.x, 32);  s.y  += __shfl_xor(s.y, 32);
    s.z  += __shfl_xor(s.z, 32);  s.w  += __shfl_xor(s.w, 32);
    ss.x += __shfl_xor(ss.x, 32); ss.y += __shfl_xor(ss.y, 32);
    ss.z += __shfl_xor(ss.z, 32); ss.w += __shfl_xor(ss.w, 32);

    const float inv = 1.0f / (float)KH;
    float partial = 0.f;
    {
        float m = s.x * inv;
        partial += sqrtf(fmaxf(ss.x * inv - m * m, 0.f) + 1e-14f);
    }
    {
        float m = s.y * inv;
        partial += sqrtf(fmaxf(ss.y * inv - m * m, 0.f) + 1e-14f);
    }
    {
        float m = s.z * inv;
        partial += sqrtf(fmaxf(ss.z * inv - m * m, 0.f) + 1e-14f);
    }
    {
        float m = s.w * inv;
        partial += sqrtf(fmaxf(ss.w * inv - m * m, 0.f) + 1e-14f);
    }

    // kw=8 bin = columns {8m..8m+7} = lanes {2m, 2m+1} (aligned pair).
    partial += __shfl_xor(partial, 1);

    if (rh == 0 && (lane & 1) == 0) {
        out[slab * W_OUT + (cg >> 1)] = partial;
    }
}

extern "C" void kernel_launch(void* const* d_in, const int* in_sizes, int n_in,
                              void* d_out, int out_size, void* d_ws, size_t ws_size,
                              hipStream_t stream) {
    const float* x = (const float*)d_in[0];
    float* out = (float*)d_out;
    adaptive_std_pool_kernel<<<SLABS / 4, 256, 0, stream>>>(x, out);
}